// Round 3
// baseline (847.273 us; speedup 1.0000x reference)
//
#include <hip/hip_runtime.h>
#include <stdint.h>

typedef unsigned int u32;
typedef unsigned long long u64;
typedef float f4v __attribute__((ext_vector_type(4)));
typedef int i4v __attribute__((ext_vector_type(4)));

#define BB 2
#define CC 32
#define DD 64
#define HH 128
#define WW 128
#define SS (DD*HH*WW)        /* 1048576 */
#define NN (BB*SS)           /* 2097152 */
#define NQ (NN/4)            /* 524288 */
#define NWORDS (NN/64)       /* 32768 */
#define EPSF 1e-12f
#define TOPN 250u

struct Ctrl {
  u32 done4, tie, bar0, bar1, bar2, bar3, pad0, pad1;
};

struct Acc {
  double ce, tp, fp, fn;
  double stdsum[CC];
  double pos_num, mis_num, fin_num;
  u64 cnt, mcnt, fcnt;
};

// ---------- reduction helpers ----------
__device__ __forceinline__ float waveRedF(float v){
#pragma unroll
  for (int o = 32; o; o >>= 1) v += __shfl_xor(v, o);
  return v;
}
__device__ __forceinline__ u32 waveRedU(u32 v){
#pragma unroll
  for (int o = 32; o; o >>= 1) v += __shfl_xor(v, o);
  return v;
}
__device__ __forceinline__ void red_d(double* dst, float v, volatile float* sh){
  int lane = threadIdx.x & 63, wid = threadIdx.x >> 6;
  v = waveRedF(v);
  if (lane == 0) sh[wid] = v;
  __syncthreads();
  if (threadIdx.x == 0){
    float t = 0.f;
    for (int i = 0; i < (int)(blockDim.x >> 6); i++) t += sh[i];
    atomicAdd(dst, (double)t);
  }
  __syncthreads();
}
__device__ __forceinline__ void red_u(u64* dst, u32 v, volatile u32* sh){
  int lane = threadIdx.x & 63, wid = threadIdx.x >> 6;
  v = waveRedU(v);
  if (lane == 0) sh[wid] = v;
  __syncthreads();
  if (threadIdx.x == 0){
    u32 t = 0;
    for (int i = 0; i < (int)(blockDim.x >> 6); i++) t += sh[i];
    atomicAdd(dst, (u64)t);
  }
  __syncthreads();
}

__device__ __forceinline__ u32 sortkey(float f){
  u32 u = __float_as_uint(f);
  return (u & 0x80000000u) ? ~u : (u | 0x80000000u);
}

// Device-scope grid barrier for a co-resident grid (persistent-kernel pattern).
// __launch_bounds__(256,2) on the caller guarantees 2 blocks/CU -> 512 blocks
// all resident on 256 CUs. Fences on both sides for cross-XCD visibility of
// plain stores (per-XCD L2 non-coherent).
__device__ __forceinline__ void gridbar(u32* bar, u32 n){
  __syncthreads();
  __threadfence();
  if (threadIdx.x == 0){
    __hip_atomic_fetch_add(bar, 1u, __ATOMIC_ACQ_REL, __HIP_MEMORY_SCOPE_AGENT);
    while (__hip_atomic_load(bar, __ATOMIC_ACQUIRE, __HIP_MEMORY_SCOPE_AGENT) < n)
      __builtin_amdgcn_s_sleep(2);
  }
  __syncthreads();
  __threadfence();
}

// Redundant per-block top-k bin selection from a finalized global histogram.
// Histogram reads use agent-scope atomic loads: within the fused persistent
// kernel the bins were atomically added by other blocks (possibly other XCDs),
// so plain cached loads are not guaranteed fresh.
__device__ __forceinline__ void select_top(u32* __restrict__ hist, u32 nbins,
                                           u32 k, u32* shres, u32* binOut, u32* kremOut){
  __syncthreads();
  if (threadIdx.x < 64){
    int lane = threadIdx.x;
    u32 running = 0; bool found = false;
    for (u32 chunk = 0; chunk * 64 < nbins && !found; chunk++){
      int bin = (int)nbins - 1 - (int)(chunk * 64 + (u32)lane);
      u32 val = (bin >= 0) ?
        __hip_atomic_load(&hist[bin], __ATOMIC_RELAXED, __HIP_MEMORY_SCOPE_AGENT) : 0u;
      u32 p = val;
#pragma unroll
      for (int o = 1; o < 64; o <<= 1){ u32 t = __shfl_up(p, o); if (lane >= o) p += t; }
      u32 tot = __shfl(p, 63);
      u32 incl = running + p, excl = incl - val;
      bool hit = (excl < k) && (incl >= k);
      u64 mb = __ballot(hit);
      if (mb){
        int hl = __ffsll((unsigned long long)mb) - 1;
        if (lane == hl){ shres[0] = (u32)bin; shres[1] = k - excl; }
        found = true;
      } else running += tot;
    }
    if (!found && lane == 0){ shres[0] = 0; shres[1] = k; }
  }
  __syncthreads();
  *binOut = shres[0]; *kremOut = shres[1];
}

// ---------- fused W+H slab dilation as a device function ----------
__device__ __forceinline__ void dilwh_slab(const u64* __restrict__ in, u64* __restrict__ out,
                                           u32 slab, u64* arr){
  u32 base = slab * 256u;
  int t = threadIdx.x;
  if (t < 128){
    u64 lo = in[base + 2 * t], hi = in[base + 2 * t + 1];
    u64 al = lo, ah = hi;
#pragma unroll
    for (int i = 0; i < 10; i++){ u64 c = al >> 63; ah = ah | (ah << 1) | c; al = al | (al << 1); }
    u64 bl = lo, bh = hi;
#pragma unroll
    for (int i = 0; i < 10; i++){ u64 c = bh << 63; bl = bl | (bl >> 1) | c; bh = bh | (bh >> 1); }
    arr[2 * t] = al | bl;
    arr[2 * t + 1] = ah | bh;
  }
  __syncthreads();
  int h = t >> 1, wj = t & 1;
  int h0 = h - 10 > 0 ? h - 10 : 0;
  int h1 = h + 10 < 127 ? h + 10 : 127;
  u64 o = 0;
  for (int hh = h0; hh <= h1; hh++) o |= arr[2 * hh + wj];
  out[base + (u32)t] = o;
  __syncthreads();
}

// ---------- K0: pbits from tgt + per-block pos counts + zero accumulators ----------
__global__ __launch_bounds__(256) void k_pre(const int* __restrict__ tgt,
                                             u64* __restrict__ pbits,
                                             u32* __restrict__ cntArr,
                                             u32* __restrict__ zptr, u32 zwords){
  __shared__ u32 nibsh[256];
  __shared__ u32 shu[4];
  if (blockIdx.x == 0){
    for (u32 i = threadIdx.x; i < zwords; i += 256u) zptr[i] = 0;
  }
  u32 cnt = 0;
#pragma unroll 1
  for (u32 it = 0; it < 4; it++){
    u32 q = blockIdx.x * 1024u + it * 256u + threadIdx.x;   // quad index
    i4v l4 = __builtin_nontemporal_load((const i4v*)(tgt + q * 4u));
    u32 nib = (l4.x ? 1u : 0u) | (l4.y ? 2u : 0u) | (l4.z ? 4u : 0u) | (l4.w ? 8u : 0u);
    cnt += __popc(nib);
    __syncthreads();             // protect nibsh reuse across iterations
    nibsh[threadIdx.x] = nib;
    __syncthreads();
    if (threadIdx.x < 16){
      u64 o = 0;
#pragma unroll
      for (int j = 0; j < 16; j++)
        o |= (u64)(nibsh[threadIdx.x * 16 + j] & 0xFu) << (4 * j);
      pbits[blockIdx.x * 64u + it * 16u + threadIdx.x] = o;
    }
  }
  int lane = threadIdx.x & 63, wid = threadIdx.x >> 6;
  cnt = waveRedU(cnt);
  if (lane == 0) shu[wid] = cnt;
  __syncthreads();
  if (threadIdx.x == 0) cntArr[blockIdx.x] = shu[0] + shu[1] + shu[2] + shu[3];
}

// ---------- K1: fused CE/dice + channel-major pos-sum of feature ----------
__global__ __launch_bounds__(256) void k_ce_std(const float* __restrict__ feat,
                                                const float* __restrict__ net,
                                                const u64* __restrict__ pbits, Acc* acc){
  __shared__ float sh[16];
  if (blockIdx.x < 64u){
    u32 bid = blockIdx.x;
    float ce = 0.f, tp = 0.f, fp = 0.f, fnn = 0.f;
#pragma unroll 1
    for (u32 it = 0; it < 32; it++){
      u32 q = bid * 8192u + it * 256u + threadIdx.x;        // quad index
      u32 nib = (u32)(pbits[q >> 4] >> ((q & 15u) << 2)) & 0xFu;
      u32 v = q * 4u;
      u32 b = v >> 20, s = v & (SS - 1);
      const float* nb = net + (size_t)(b * 2) * SS + s;
      f4v x0 = __builtin_nontemporal_load((const f4v*)(nb));
      f4v x1 = __builtin_nontemporal_load((const f4v*)(nb + SS));
      float xs0[4] = {x0.x, x0.y, x0.z, x0.w};
      float xs1[4] = {x1.x, x1.y, x1.z, x1.w};
#pragma unroll
      for (int j = 0; j < 4; j++){
        int lab = (nib >> j) & 1;
        float m = fmaxf(xs0[j], xs1[j]);
        float lse = m + logf(expf(xs0[j] - m) + expf(xs1[j] - m));
        ce += lse - (lab ? xs1[j] : xs0[j]);
        float p1 = expf(xs1[j] - lse);
        if (lab){ tp += p1; fnn += 1.0f - p1; } else fp += p1;
      }
    }
    int lane = threadIdx.x & 63, wid = threadIdx.x >> 6;
    ce = waveRedF(ce); tp = waveRedF(tp); fp = waveRedF(fp); fnn = waveRedF(fnn);
    if (lane == 0){ sh[wid] = ce; sh[4 + wid] = tp; sh[8 + wid] = fp; sh[12 + wid] = fnn; }
    __syncthreads();
    if (threadIdx.x == 0){
      atomicAdd(&acc->ce, (double)(sh[0] + sh[1] + sh[2] + sh[3]));
      atomicAdd(&acc->tp, (double)(sh[4] + sh[5] + sh[6] + sh[7]));
      atomicAdd(&acc->fp, (double)(sh[8] + sh[9] + sh[10] + sh[11]));
      atomicAdd(&acc->fn, (double)(sh[12] + sh[13] + sh[14] + sh[15]));
    }
  } else {
    u32 bx = blockIdx.x - 64u;
    u32 c = bx & 31u;
    u32 chunk = bx >> 5;                // 0..31
    u32 vbase = chunk * 65536u;
    u32 b = vbase >> 20;
    u32 s0 = vbase & (SS - 1);
    const float* fp_ = feat + (size_t)b * CC * SS + (size_t)c * SS + s0;
    const u64* pb = pbits + (vbase >> 6);
    float a = 0.f;
#pragma unroll 8
    for (u32 i = 0; i < 64; i++){
      u32 off = i * 1024u + threadIdx.x * 4u;
      float4 f = *(const float4*)(fp_ + off);
      u32 bits = (u32)(pb[off >> 6] >> (off & 63u)) & 0xFu;
      if (bits & 1u) a += f.x;
      if (bits & 2u) a += f.y;
      if (bits & 4u) a += f.z;
      if (bits & 8u) a += f.w;
    }
    int lane = threadIdx.x & 63, wid = threadIdx.x >> 6;
    a = waveRedF(a);
    if (lane == 0) sh[wid] = a;
    __syncthreads();
    if (threadIdx.x == 0)
      atomicAdd(&acc->stdsum[c], (double)(sh[0] + sh[1] + sh[2] + sh[3]));
  }
}

// ---------- K2: persistent fused tail ----------
// sim+hist | bar | histL2 + P-dilation | bar | mark | bar | HS-dilation | bar | final.
// 512 blocks @ 2 blocks/CU co-resident (launch_bounds(256,2)); replaces 5
// dispatches with 1.
__global__ __launch_bounds__(256, 2) void k_simtail(const float* __restrict__ feat,
                                                    const u64* __restrict__ pbits,
                                                    const u32* __restrict__ cntArr,
                                                    Acc* acc, float* __restrict__ sim,
                                                    u32* __restrict__ h1,
                                                    u32* __restrict__ h2,
                                                    u64* __restrict__ T1P,
                                                    u64* __restrict__ hs,
                                                    u64* __restrict__ T1H,
                                                    Ctrl* ctrl, float* out){
  __shared__ float st[CC];
  __shared__ u32 lh[2048];
  __shared__ u64 arr[256];
  __shared__ u32 shres[2];
  __shared__ float shf[4];
  __shared__ u32 shu[4];
  __shared__ u32 scnt;
  __shared__ int amLast;

  // ---- prologue: global cnt + normalized std direction ----
  if (threadIdx.x < 64){
    u32 sc = 0;
#pragma unroll
    for (int i = 0; i < 8; i++) sc += cntArr[threadIdx.x * 8 + i];
    sc = waveRedU(sc);
    if (threadIdx.x == 0) scnt = sc;
  }
  __syncthreads();
  u32 cnt = scnt;
  if (blockIdx.x == 0 && threadIdx.x == 0)
    __hip_atomic_store(&acc->cnt, (u64)cnt, __ATOMIC_RELAXED, __HIP_MEMORY_SCOPE_AGENT);
  {
    float sv = 0.f;
    if (threadIdx.x < CC && cnt) sv = (float)(acc->stdsum[threadIdx.x] / (double)cnt);
    if (threadIdx.x < 64){
      float t = waveRedF(sv * sv);
      float d = fmaxf(sqrtf(t), EPSF);
      if (threadIdx.x < CC) st[threadIdx.x] = sv / d;
    }
  }
  for (u32 i = threadIdx.x; i < 2048u; i += 256u) lh[i] = 0;
  __syncthreads();

  // ---- phase 1: sim + pos_num + level-1 histogram ----
  {
    u32 vbase = (511u - blockIdx.x) * 4096u;
    u32 b = vbase >> 20;
    u32 s0 = vbase & (SS - 1);
    const float* fp = feat + (size_t)b * CC * SS + s0;
    float4 dt[4], n2[4];
#pragma unroll
    for (int g = 0; g < 4; g++){
      dt[g].x = dt[g].y = dt[g].z = dt[g].w = 0.f;
      n2[g].x = n2[g].y = n2[g].z = n2[g].w = 0.f;
    }
#pragma unroll 2
    for (u32 c = 0; c < CC; c++){
      float w = st[c];
      const float* fc = fp + (size_t)c * SS;
      float4 f[4];
#pragma unroll
      for (int g = 0; g < 4; g++)
        f[g] = *(const float4*)(fc + (u32)g * 1024u + threadIdx.x * 4u);
#pragma unroll
      for (int g = 0; g < 4; g++){
        dt[g].x += f[g].x * w; dt[g].y += f[g].y * w;
        dt[g].z += f[g].z * w; dt[g].w += f[g].w * w;
        n2[g].x += f[g].x * f[g].x; n2[g].y += f[g].y * f[g].y;
        n2[g].z += f[g].z * f[g].z; n2[g].w += f[g].w * f[g].w;
      }
    }
    float pn = 0.f;
#pragma unroll
    for (int g = 0; g < 4; g++){
      u32 off = (u32)g * 1024u + threadIdx.x * 4u;
      u32 v = vbase + off;
      float4 sm;
      sm.x = dt[g].x / fmaxf(sqrtf(n2[g].x), EPSF);
      sm.y = dt[g].y / fmaxf(sqrtf(n2[g].y), EPSF);
      sm.z = dt[g].z / fmaxf(sqrtf(n2[g].z), EPSF);
      sm.w = dt[g].w / fmaxf(sqrtf(n2[g].w), EPSF);
      *(float4*)(sim + v) = sm;
      u32 bits = (u32)(pbits[v >> 6] >> (v & 63u)) & 0xFu;
      float ss[4] = {sm.x, sm.y, sm.z, sm.w};
#pragma unroll
      for (int j = 0; j < 4; j++){
        if ((bits >> j) & 1u) pn += 1.f - ss[j];
        else atomicAdd(&lh[sortkey(ss[j]) >> 21], 1u);
      }
    }
    __syncthreads();
    for (u32 i = threadIdx.x; i < 2048u; i += 256u)
      if (lh[i]) atomicAdd(&h1[i], lh[i]);
    red_d(&acc->pos_num, pn, shf);
  }
  gridbar(&ctrl->bar0, 512u);     // h1 + sim finalized

  // ---- phase 2: level-2 histogram + P W+H dilation ----
  {
    if (blockIdx.x < 128u) dilwh_slab(pbits, T1P, blockIdx.x, arr);
    u32 p1, k1;
    select_top(h1, 2048, TOPN, shres, &p1, &k1);
    for (u32 i = threadIdx.x; i < 2048u; i += 256u) lh[i] = 0;
    __syncthreads();
    const u32 stride = 512u * 256u;
#pragma unroll 1
    for (u32 it = 0; it < 4; it++){
      u32 q = blockIdx.x * 256u + threadIdx.x + it * stride;
      u32 nib = (u32)(pbits[q >> 4] >> ((q & 15u) << 2)) & 0xFu;
      float4 s4 = *(const float4*)(sim + q * 4u);
      float ss[4] = {s4.x, s4.y, s4.z, s4.w};
#pragma unroll
      for (int j = 0; j < 4; j++){
        if (!((nib >> j) & 1u)){
          u32 key = sortkey(ss[j]);
          if ((key >> 21) == p1) atomicAdd(&lh[(key >> 10) & 2047u], 1u);
        }
      }
    }
    __syncthreads();
    for (u32 i = threadIdx.x; i < 2048u; i += 256u)
      if (lh[i]) atomicAdd(&h2[i], lh[i]);
  }
  gridbar(&ctrl->bar1, 512u);     // h2 + T1P finalized

  // ---- phase 3: mark top-250 seeds ----
  {
    u32 p1, k1, b2, k2;
    select_top(h1, 2048, TOPN, shres, &p1, &k1);
    select_top(h2, 2048, k1, shres, &b2, &k2);
    u32 p12 = (p1 << 11) | b2;
    int lane = threadIdx.x & 63;
    const u32 stride = 512u * 256u;
#pragma unroll 1
    for (u32 it = 0; it < 16; it++){
      u32 v = blockIdx.x * 256u + threadIdx.x + it * stride;
      u64 w = pbits[v >> 6];
      bool neg = !((w >> (v & 63u)) & 1ull);
      bool seed = false;
      if (neg){
        u32 pref = sortkey(sim[v]) >> 10;
        if (pref > p12) seed = true;
        else if (pref == p12){
          u32 old = atomicAdd(&ctrl->tie, 1u);
          if (old < k2) seed = true;
        }
      }
      u64 mb = __ballot(seed);
      if (lane == 0) hs[v >> 6] = mb;
    }
  }
  gridbar(&ctrl->bar2, 512u);     // HS finalized

  // ---- phase 4: HS W+H dilation ----
  if (blockIdx.x < 128u) dilwh_slab(hs, T1H, blockIdx.x, arr);
  gridbar(&ctrl->bar3, 512u);     // T1H finalized
  if (blockIdx.x >= 128u) return;

  // ---- phase 5: inline D-dilation + mis/fin sums + combine (blocks 0..127) ----
  {
    u32 wi = blockIdx.x * 256u + threadIdx.x;   // one 64-voxel word per thread
    u32 wj = wi & 1u;
    u32 row = wi >> 1;                           // b*8192 + d*128 + h
    int h = (int)(row & 127u);
    int d = (int)((row >> 7) & 63u);
    u32 b = row >> 13;
    int d0 = d - 10 > 0 ? d - 10 : 0;
    int d1 = d + 10 < 63 ? d + 10 : 63;
    const u64* bp = T1P + ((size_t)(b << 13) + (u32)h) * 2 + wj;
    const u64* bh = T1H + ((size_t)(b << 13) + (u32)h) * 2 + wj;
    u64 dpw = 0, dhw = 0;
    for (int dd = d0; dd <= d1; dd++){
      dpw |= bp[(size_t)dd * 256];
      dhw |= bh[(size_t)dd * 256];
    }
    u64 pw = pbits[wi];
    u64 mis = dpw & ~pw;
    u64 fin = dhw & ~pw;
    float mn = 0.f, fnm = 0.f;
    u32 mc = (u32)__popcll(mis), fc = (u32)__popcll(fin);
    const float* sp = sim + (size_t)wi * 64u;
#pragma unroll 1
    for (int jj = 0; jj < 16; jj++){
      float4 s4 = *(const float4*)(sp + jj * 4);
      float ss[4] = {s4.x, s4.y, s4.z, s4.w};
#pragma unroll
      for (int j = 0; j < 4; j++){
        int bit = jj * 4 + j;
        float r = fmaxf(ss[j], 0.f);
        if ((mis >> bit) & 1ull) mn += r;
        if ((fin >> bit) & 1ull) fnm += r;
      }
    }
    red_d(&acc->mis_num, mn, shf);
    red_d(&acc->fin_num, fnm, shf);
    red_u(&acc->mcnt, mc, shu);
    red_u(&acc->fcnt, fc, shu);
    __threadfence();
    if (threadIdx.x == 0) amLast = (atomicAdd(&ctrl->done4, 1u) == 127u);
    __syncthreads();
    if (amLast && threadIdx.x == 0){
      double ce = acc->ce / (double)NN;
      double tp = acc->tp, fp = acc->fp, fn = acc->fn;
      double dc1 = (2.0 * tp + 1e-5) / (2.0 * tp + fp + fn + 1e-5 + 1e-8);
      u64 cnt2 = acc->cnt;
      double pos_loss = cnt2 ? (atomicAdd(&acc->pos_num, 0.0) / (double)cnt2) : 0.0;
      u64 mcnt = atomicAdd(&acc->mcnt, 0ull);
      u64 fcnt = atomicAdd(&acc->fcnt, 0ull);
      double mis_loss = mcnt ? (atomicAdd(&acc->mis_num, 0.0) / (double)mcnt) : 0.0;
      double neg_loss = fcnt ? (atomicAdd(&acc->fin_num, 0.0) / (double)fcnt) : 0.0;
      out[0] = (float)(ce - dc1 + 5.0 * (pos_loss + mis_loss + neg_loss));
    }
  }
}

extern "C" void kernel_launch(void* const* d_in, const int* in_sizes, int n_in,
                              void* d_out, int out_size, void* d_ws, size_t ws_size,
                              hipStream_t stream){
  (void)in_sizes; (void)n_in; (void)out_size; (void)ws_size;
  const float* feat = (const float*)d_in[0];
  const float* net  = (const float*)d_in[1];
  const int*   tgt  = (const int*)d_in[2];
  float* out = (float*)d_out;
  char* ws = (char*)d_ws;

  size_t off = 0;
  auto take = [&](size_t bytes) -> void* {
    void* p = (void*)(ws + off);
    off += (bytes + 255) & ~(size_t)255;
    return p;
  };
  float* sim = (float*)take((size_t)NN * 4);
  u64* P   = (u64*)take((size_t)NWORDS * 8);
  u64* T1P = (u64*)take((size_t)NWORDS * 8);
  u64* HS  = (u64*)take((size_t)NWORDS * 8);
  u64* T1H = (u64*)take((size_t)NWORDS * 8);
  u32* cntArr = (u32*)take(512 * 4);
  size_t zstart = off;
  u32* h1 = (u32*)take(2048 * 4);
  u32* h2 = (u32*)take(2048 * 4);
  Ctrl* ctrl = (Ctrl*)take(sizeof(Ctrl));
  Acc* acc = (Acc*)take(sizeof(Acc));
  u32 zwords = (u32)((off - zstart) >> 2);

  // 3 dispatches (was 7): whole tail is one persistent kernel.
  k_pre<<<512, 256, 0, stream>>>(tgt, P, cntArr, (u32*)(ws + zstart), zwords);
  k_ce_std<<<1088, 256, 0, stream>>>(feat, net, P, acc);
  k_simtail<<<512, 256, 0, stream>>>(feat, P, cntArr, acc, sim, h1, h2, T1P, HS, T1H, ctrl, out);
}

// Round 4
// 823.165 us; speedup vs baseline: 1.0293x; 1.0293x over previous
//
#include <hip/hip_runtime.h>
#include <stdint.h>

typedef unsigned int u32;
typedef unsigned long long u64;
typedef float f4v __attribute__((ext_vector_type(4)));
typedef int i4v __attribute__((ext_vector_type(4)));

#define BB 2
#define CC 32
#define DD 64
#define HH 128
#define WW 128
#define SS (DD*HH*WW)        /* 1048576 */
#define NN (BB*SS)           /* 2097152 */
#define NQ (NN/4)            /* 524288 */
#define NWORDS (NN/64)       /* 32768 */
#define EPSF 1e-12f
#define TOPN 250u

struct Ctrl {
  u32 done4, tie, pad0, pad1;
};

struct Acc {
  double ce, tp, fp, fn;
  double stdsum[CC];
  double pos_num, mis_num, fin_num;
  u64 cnt, mcnt, fcnt;
};

// ---------- reduction helpers ----------
__device__ __forceinline__ float waveRedF(float v){
#pragma unroll
  for (int o = 32; o; o >>= 1) v += __shfl_xor(v, o);
  return v;
}
__device__ __forceinline__ u32 waveRedU(u32 v){
#pragma unroll
  for (int o = 32; o; o >>= 1) v += __shfl_xor(v, o);
  return v;
}
__device__ __forceinline__ void red_d(double* dst, float v, volatile float* sh){
  int lane = threadIdx.x & 63, wid = threadIdx.x >> 6;
  v = waveRedF(v);
  if (lane == 0) sh[wid] = v;
  __syncthreads();
  if (threadIdx.x == 0){
    float t = 0.f;
    for (int i = 0; i < (int)(blockDim.x >> 6); i++) t += sh[i];
    atomicAdd(dst, (double)t);
  }
  __syncthreads();
}
__device__ __forceinline__ void red_u(u64* dst, u32 v, volatile u32* sh){
  int lane = threadIdx.x & 63, wid = threadIdx.x >> 6;
  v = waveRedU(v);
  if (lane == 0) sh[wid] = v;
  __syncthreads();
  if (threadIdx.x == 0){
    u32 t = 0;
    for (int i = 0; i < (int)(blockDim.x >> 6); i++) t += sh[i];
    atomicAdd(dst, (u64)t);
  }
  __syncthreads();
}

__device__ __forceinline__ u32 sortkey(float f){
  u32 u = __float_as_uint(f);
  return (u & 0x80000000u) ? ~u : (u | 0x80000000u);
}

// Device-scope grid barrier for a co-resident grid (persistent-kernel pattern).
// FIX vs R3: RELAXED polls (no per-poll cache invalidate) + RELAXED arrival +
// s_sleep(32) backoff. Cross-XCD data visibility is carried entirely by the
// __threadfence() pair (release before arrival, acquire after observation) —
// the same fences R3 proved correct (absmax 0). Each bar sits on its own
// 128-B line (bars array, stride 32 u32).
__device__ __forceinline__ void gridbar(u32* bar, u32 n){
  __syncthreads();
  __threadfence();
  if (threadIdx.x == 0){
    __hip_atomic_fetch_add(bar, 1u, __ATOMIC_RELAXED, __HIP_MEMORY_SCOPE_AGENT);
    while (__hip_atomic_load(bar, __ATOMIC_RELAXED, __HIP_MEMORY_SCOPE_AGENT) < n)
      __builtin_amdgcn_s_sleep(32);
  }
  __syncthreads();
  __threadfence();
}

// Redundant per-block top-k bin selection from a finalized global histogram.
__device__ __forceinline__ void select_top(u32* __restrict__ hist, u32 nbins,
                                           u32 k, u32* shres, u32* binOut, u32* kremOut){
  __syncthreads();
  if (threadIdx.x < 64){
    int lane = threadIdx.x;
    u32 running = 0; bool found = false;
    for (u32 chunk = 0; chunk * 64 < nbins && !found; chunk++){
      int bin = (int)nbins - 1 - (int)(chunk * 64 + (u32)lane);
      u32 val = (bin >= 0) ?
        __hip_atomic_load(&hist[bin], __ATOMIC_RELAXED, __HIP_MEMORY_SCOPE_AGENT) : 0u;
      u32 p = val;
#pragma unroll
      for (int o = 1; o < 64; o <<= 1){ u32 t = __shfl_up(p, o); if (lane >= o) p += t; }
      u32 tot = __shfl(p, 63);
      u32 incl = running + p, excl = incl - val;
      bool hit = (excl < k) && (incl >= k);
      u64 mb = __ballot(hit);
      if (mb){
        int hl = __ffsll((unsigned long long)mb) - 1;
        if (lane == hl){ shres[0] = (u32)bin; shres[1] = k - excl; }
        found = true;
      } else running += tot;
    }
    if (!found && lane == 0){ shres[0] = 0; shres[1] = k; }
  }
  __syncthreads();
  *binOut = shres[0]; *kremOut = shres[1];
}

// ---------- fused W+H slab dilation as a device function ----------
__device__ __forceinline__ void dilwh_slab(const u64* __restrict__ in, u64* __restrict__ out,
                                           u32 slab, u64* arr){
  u32 base = slab * 256u;
  int t = threadIdx.x;
  if (t < 128){
    u64 lo = in[base + 2 * t], hi = in[base + 2 * t + 1];
    u64 al = lo, ah = hi;
#pragma unroll
    for (int i = 0; i < 10; i++){ u64 c = al >> 63; ah = ah | (ah << 1) | c; al = al | (al << 1); }
    u64 bl = lo, bh = hi;
#pragma unroll
    for (int i = 0; i < 10; i++){ u64 c = bh << 63; bl = bl | (bl >> 1) | c; bh = bh | (bh >> 1); }
    arr[2 * t] = al | bl;
    arr[2 * t + 1] = ah | bh;
  }
  __syncthreads();
  int h = t >> 1, wj = t & 1;
  int h0 = h - 10 > 0 ? h - 10 : 0;
  int h1 = h + 10 < 127 ? h + 10 : 127;
  u64 o = 0;
  for (int hh = h0; hh <= h1; hh++) o |= arr[2 * hh + wj];
  out[base + (u32)t] = o;
  __syncthreads();
}

// ---------- K0: pbits from tgt + per-block pos counts + zero accumulators ----------
__global__ __launch_bounds__(256) void k_pre(const int* __restrict__ tgt,
                                             u64* __restrict__ pbits,
                                             u32* __restrict__ cntArr,
                                             u32* __restrict__ zptr, u32 zwords){
  __shared__ u32 nibsh[256];
  __shared__ u32 shu[4];
  if (blockIdx.x == 0){
    for (u32 i = threadIdx.x; i < zwords; i += 256u) zptr[i] = 0;
  }
  u32 cnt = 0;
#pragma unroll 1
  for (u32 it = 0; it < 4; it++){
    u32 q = blockIdx.x * 1024u + it * 256u + threadIdx.x;   // quad index
    i4v l4 = __builtin_nontemporal_load((const i4v*)(tgt + q * 4u));
    u32 nib = (l4.x ? 1u : 0u) | (l4.y ? 2u : 0u) | (l4.z ? 4u : 0u) | (l4.w ? 8u : 0u);
    cnt += __popc(nib);
    __syncthreads();             // protect nibsh reuse across iterations
    nibsh[threadIdx.x] = nib;
    __syncthreads();
    if (threadIdx.x < 16){
      u64 o = 0;
#pragma unroll
      for (int j = 0; j < 16; j++)
        o |= (u64)(nibsh[threadIdx.x * 16 + j] & 0xFu) << (4 * j);
      pbits[blockIdx.x * 64u + it * 16u + threadIdx.x] = o;
    }
  }
  int lane = threadIdx.x & 63, wid = threadIdx.x >> 6;
  cnt = waveRedU(cnt);
  if (lane == 0) shu[wid] = cnt;
  __syncthreads();
  if (threadIdx.x == 0) cntArr[blockIdx.x] = shu[0] + shu[1] + shu[2] + shu[3];
}

// ---------- K1: fused CE/dice + channel-major pos-sum of feature ----------
__global__ __launch_bounds__(256) void k_ce_std(const float* __restrict__ feat,
                                                const float* __restrict__ net,
                                                const u64* __restrict__ pbits, Acc* acc){
  __shared__ float sh[16];
  if (blockIdx.x < 64u){
    u32 bid = blockIdx.x;
    float ce = 0.f, tp = 0.f, fp = 0.f, fnn = 0.f;
#pragma unroll 1
    for (u32 it = 0; it < 32; it++){
      u32 q = bid * 8192u + it * 256u + threadIdx.x;        // quad index
      u32 nib = (u32)(pbits[q >> 4] >> ((q & 15u) << 2)) & 0xFu;
      u32 v = q * 4u;
      u32 b = v >> 20, s = v & (SS - 1);
      const float* nb = net + (size_t)(b * 2) * SS + s;
      f4v x0 = __builtin_nontemporal_load((const f4v*)(nb));
      f4v x1 = __builtin_nontemporal_load((const f4v*)(nb + SS));
      float xs0[4] = {x0.x, x0.y, x0.z, x0.w};
      float xs1[4] = {x1.x, x1.y, x1.z, x1.w};
#pragma unroll
      for (int j = 0; j < 4; j++){
        int lab = (nib >> j) & 1;
        float m = fmaxf(xs0[j], xs1[j]);
        float lse = m + logf(expf(xs0[j] - m) + expf(xs1[j] - m));
        ce += lse - (lab ? xs1[j] : xs0[j]);
        float p1 = expf(xs1[j] - lse);
        if (lab){ tp += p1; fnn += 1.0f - p1; } else fp += p1;
      }
    }
    int lane = threadIdx.x & 63, wid = threadIdx.x >> 6;
    ce = waveRedF(ce); tp = waveRedF(tp); fp = waveRedF(fp); fnn = waveRedF(fnn);
    if (lane == 0){ sh[wid] = ce; sh[4 + wid] = tp; sh[8 + wid] = fp; sh[12 + wid] = fnn; }
    __syncthreads();
    if (threadIdx.x == 0){
      atomicAdd(&acc->ce, (double)(sh[0] + sh[1] + sh[2] + sh[3]));
      atomicAdd(&acc->tp, (double)(sh[4] + sh[5] + sh[6] + sh[7]));
      atomicAdd(&acc->fp, (double)(sh[8] + sh[9] + sh[10] + sh[11]));
      atomicAdd(&acc->fn, (double)(sh[12] + sh[13] + sh[14] + sh[15]));
    }
  } else {
    u32 bx = blockIdx.x - 64u;
    u32 c = bx & 31u;
    u32 chunk = bx >> 5;                // 0..31
    u32 vbase = chunk * 65536u;
    u32 b = vbase >> 20;
    u32 s0 = vbase & (SS - 1);
    const float* fp_ = feat + (size_t)b * CC * SS + (size_t)c * SS + s0;
    const u64* pb = pbits + (vbase >> 6);
    float a = 0.f;
#pragma unroll 8
    for (u32 i = 0; i < 64; i++){
      u32 off = i * 1024u + threadIdx.x * 4u;
      float4 f = *(const float4*)(fp_ + off);
      u32 bits = (u32)(pb[off >> 6] >> (off & 63u)) & 0xFu;
      if (bits & 1u) a += f.x;
      if (bits & 2u) a += f.y;
      if (bits & 4u) a += f.z;
      if (bits & 8u) a += f.w;
    }
    int lane = threadIdx.x & 63, wid = threadIdx.x >> 6;
    a = waveRedF(a);
    if (lane == 0) sh[wid] = a;
    __syncthreads();
    if (threadIdx.x == 0)
      atomicAdd(&acc->stdsum[c], (double)(sh[0] + sh[1] + sh[2] + sh[3]));
  }
}

// ---------- K2: persistent fused tail ----------
// sim+hist | bar | histL2 + P-dilation | bar | mark | bar | HS-dilation | bar | final.
// 512 blocks @ 2 blocks/CU co-resident; replaces 5 dispatches with 1.
__global__ __launch_bounds__(256, 2) void k_simtail(const float* __restrict__ feat,
                                                    const u64* __restrict__ pbits,
                                                    const u32* __restrict__ cntArr,
                                                    Acc* acc, float* __restrict__ sim,
                                                    u32* __restrict__ h1,
                                                    u32* __restrict__ h2,
                                                    u64* __restrict__ T1P,
                                                    u64* __restrict__ hs,
                                                    u64* __restrict__ T1H,
                                                    u32* __restrict__ bars,
                                                    Ctrl* ctrl, float* out){
  __shared__ float st[CC];
  __shared__ u32 lh[2048];
  __shared__ u64 arr[256];
  __shared__ u32 shres[2];
  __shared__ float shf[4];
  __shared__ u32 shu[4];
  __shared__ u32 scnt;
  __shared__ int amLast;

  // ---- prologue: global cnt + normalized std direction ----
  if (threadIdx.x < 64){
    u32 sc = 0;
#pragma unroll
    for (int i = 0; i < 8; i++) sc += cntArr[threadIdx.x * 8 + i];
    sc = waveRedU(sc);
    if (threadIdx.x == 0) scnt = sc;
  }
  __syncthreads();
  u32 cnt = scnt;
  if (blockIdx.x == 0 && threadIdx.x == 0)
    __hip_atomic_store(&acc->cnt, (u64)cnt, __ATOMIC_RELAXED, __HIP_MEMORY_SCOPE_AGENT);
  {
    float sv = 0.f;
    if (threadIdx.x < CC && cnt) sv = (float)(acc->stdsum[threadIdx.x] / (double)cnt);
    if (threadIdx.x < 64){
      float t = waveRedF(sv * sv);
      float d = fmaxf(sqrtf(t), EPSF);
      if (threadIdx.x < CC) st[threadIdx.x] = sv / d;
    }
  }
  for (u32 i = threadIdx.x; i < 2048u; i += 256u) lh[i] = 0;
  __syncthreads();

  // ---- phase 1: sim + pos_num + level-1 histogram ----
  {
    u32 vbase = (511u - blockIdx.x) * 4096u;
    u32 b = vbase >> 20;
    u32 s0 = vbase & (SS - 1);
    const float* fp = feat + (size_t)b * CC * SS + s0;
    float4 dt[4], n2[4];
#pragma unroll
    for (int g = 0; g < 4; g++){
      dt[g].x = dt[g].y = dt[g].z = dt[g].w = 0.f;
      n2[g].x = n2[g].y = n2[g].z = n2[g].w = 0.f;
    }
#pragma unroll 2
    for (u32 c = 0; c < CC; c++){
      float w = st[c];
      const float* fc = fp + (size_t)c * SS;
      float4 f[4];
#pragma unroll
      for (int g = 0; g < 4; g++)
        f[g] = *(const float4*)(fc + (u32)g * 1024u + threadIdx.x * 4u);
#pragma unroll
      for (int g = 0; g < 4; g++){
        dt[g].x += f[g].x * w; dt[g].y += f[g].y * w;
        dt[g].z += f[g].z * w; dt[g].w += f[g].w * w;
        n2[g].x += f[g].x * f[g].x; n2[g].y += f[g].y * f[g].y;
        n2[g].z += f[g].z * f[g].z; n2[g].w += f[g].w * f[g].w;
      }
    }
    float pn = 0.f;
#pragma unroll
    for (int g = 0; g < 4; g++){
      u32 off = (u32)g * 1024u + threadIdx.x * 4u;
      u32 v = vbase + off;
      float4 sm;
      sm.x = dt[g].x / fmaxf(sqrtf(n2[g].x), EPSF);
      sm.y = dt[g].y / fmaxf(sqrtf(n2[g].y), EPSF);
      sm.z = dt[g].z / fmaxf(sqrtf(n2[g].z), EPSF);
      sm.w = dt[g].w / fmaxf(sqrtf(n2[g].w), EPSF);
      *(float4*)(sim + v) = sm;
      u32 bits = (u32)(pbits[v >> 6] >> (v & 63u)) & 0xFu;
      float ss[4] = {sm.x, sm.y, sm.z, sm.w};
#pragma unroll
      for (int j = 0; j < 4; j++){
        if ((bits >> j) & 1u) pn += 1.f - ss[j];
        else atomicAdd(&lh[sortkey(ss[j]) >> 21], 1u);
      }
    }
    __syncthreads();
    for (u32 i = threadIdx.x; i < 2048u; i += 256u)
      if (lh[i]) atomicAdd(&h1[i], lh[i]);
    red_d(&acc->pos_num, pn, shf);
  }
  gridbar(bars + 0, 512u);        // h1 + sim finalized

  // ---- phase 2: level-2 histogram + P W+H dilation ----
  {
    if (blockIdx.x < 128u) dilwh_slab(pbits, T1P, blockIdx.x, arr);
    u32 p1, k1;
    select_top(h1, 2048, TOPN, shres, &p1, &k1);
    for (u32 i = threadIdx.x; i < 2048u; i += 256u) lh[i] = 0;
    __syncthreads();
    const u32 stride = 512u * 256u;
#pragma unroll 1
    for (u32 it = 0; it < 4; it++){
      u32 q = blockIdx.x * 256u + threadIdx.x + it * stride;
      u32 nib = (u32)(pbits[q >> 4] >> ((q & 15u) << 2)) & 0xFu;
      float4 s4 = *(const float4*)(sim + q * 4u);
      float ss[4] = {s4.x, s4.y, s4.z, s4.w};
#pragma unroll
      for (int j = 0; j < 4; j++){
        if (!((nib >> j) & 1u)){
          u32 key = sortkey(ss[j]);
          if ((key >> 21) == p1) atomicAdd(&lh[(key >> 10) & 2047u], 1u);
        }
      }
    }
    __syncthreads();
    for (u32 i = threadIdx.x; i < 2048u; i += 256u)
      if (lh[i]) atomicAdd(&h2[i], lh[i]);
  }
  gridbar(bars + 32, 512u);       // h2 + T1P finalized

  // ---- phase 3: mark top-250 seeds ----
  {
    u32 p1, k1, b2, k2;
    select_top(h1, 2048, TOPN, shres, &p1, &k1);
    select_top(h2, 2048, k1, shres, &b2, &k2);
    u32 p12 = (p1 << 11) | b2;
    int lane = threadIdx.x & 63;
    const u32 stride = 512u * 256u;
#pragma unroll 1
    for (u32 it = 0; it < 16; it++){
      u32 v = blockIdx.x * 256u + threadIdx.x + it * stride;
      u64 w = pbits[v >> 6];
      bool neg = !((w >> (v & 63u)) & 1ull);
      bool seed = false;
      if (neg){
        u32 pref = sortkey(sim[v]) >> 10;
        if (pref > p12) seed = true;
        else if (pref == p12){
          u32 old = atomicAdd(&ctrl->tie, 1u);
          if (old < k2) seed = true;
        }
      }
      u64 mb = __ballot(seed);
      if (lane == 0) hs[v >> 6] = mb;
    }
  }
  gridbar(bars + 64, 512u);       // HS finalized

  // ---- phase 4: HS W+H dilation ----
  if (blockIdx.x < 128u) dilwh_slab(hs, T1H, blockIdx.x, arr);
  gridbar(bars + 96, 512u);       // T1H finalized
  if (blockIdx.x >= 128u) return;

  // ---- phase 5: inline D-dilation + mis/fin sums + combine (blocks 0..127) ----
  {
    u32 wi = blockIdx.x * 256u + threadIdx.x;   // one 64-voxel word per thread
    u32 wj = wi & 1u;
    u32 row = wi >> 1;                           // b*8192 + d*128 + h
    int h = (int)(row & 127u);
    int d = (int)((row >> 7) & 63u);
    u32 b = row >> 13;
    int d0 = d - 10 > 0 ? d - 10 : 0;
    int d1 = d + 10 < 63 ? d + 10 : 63;
    const u64* bp = T1P + ((size_t)(b << 13) + (u32)h) * 2 + wj;
    const u64* bh = T1H + ((size_t)(b << 13) + (u32)h) * 2 + wj;
    u64 dpw = 0, dhw = 0;
    for (int dd = d0; dd <= d1; dd++){
      dpw |= bp[(size_t)dd * 256];
      dhw |= bh[(size_t)dd * 256];
    }
    u64 pw = pbits[wi];
    u64 mis = dpw & ~pw;
    u64 fin = dhw & ~pw;
    float mn = 0.f, fnm = 0.f;
    u32 mc = (u32)__popcll(mis), fc = (u32)__popcll(fin);
    const float* sp = sim + (size_t)wi * 64u;
#pragma unroll 1
    for (int jj = 0; jj < 16; jj++){
      float4 s4 = *(const float4*)(sp + jj * 4);
      float ss[4] = {s4.x, s4.y, s4.z, s4.w};
#pragma unroll
      for (int j = 0; j < 4; j++){
        int bit = jj * 4 + j;
        float r = fmaxf(ss[j], 0.f);
        if ((mis >> bit) & 1ull) mn += r;
        if ((fin >> bit) & 1ull) fnm += r;
      }
    }
    red_d(&acc->mis_num, mn, shf);
    red_d(&acc->fin_num, fnm, shf);
    red_u(&acc->mcnt, mc, shu);
    red_u(&acc->fcnt, fc, shu);
    __threadfence();
    if (threadIdx.x == 0) amLast = (atomicAdd(&ctrl->done4, 1u) == 127u);
    __syncthreads();
    if (amLast && threadIdx.x == 0){
      double ce = acc->ce / (double)NN;
      double tp = acc->tp, fp = acc->fp, fn = acc->fn;
      double dc1 = (2.0 * tp + 1e-5) / (2.0 * tp + fp + fn + 1e-5 + 1e-8);
      u64 cnt2 = acc->cnt;
      double pos_loss = cnt2 ? (atomicAdd(&acc->pos_num, 0.0) / (double)cnt2) : 0.0;
      u64 mcnt = atomicAdd(&acc->mcnt, 0ull);
      u64 fcnt = atomicAdd(&acc->fcnt, 0ull);
      double mis_loss = mcnt ? (atomicAdd(&acc->mis_num, 0.0) / (double)mcnt) : 0.0;
      double neg_loss = fcnt ? (atomicAdd(&acc->fin_num, 0.0) / (double)fcnt) : 0.0;
      out[0] = (float)(ce - dc1 + 5.0 * (pos_loss + mis_loss + neg_loss));
    }
  }
}

extern "C" void kernel_launch(void* const* d_in, const int* in_sizes, int n_in,
                              void* d_out, int out_size, void* d_ws, size_t ws_size,
                              hipStream_t stream){
  (void)in_sizes; (void)n_in; (void)out_size; (void)ws_size;
  const float* feat = (const float*)d_in[0];
  const float* net  = (const float*)d_in[1];
  const int*   tgt  = (const int*)d_in[2];
  float* out = (float*)d_out;
  char* ws = (char*)d_ws;

  size_t off = 0;
  auto take = [&](size_t bytes) -> void* {
    void* p = (void*)(ws + off);
    off += (bytes + 255) & ~(size_t)255;
    return p;
  };
  float* sim = (float*)take((size_t)NN * 4);
  u64* P   = (u64*)take((size_t)NWORDS * 8);
  u64* T1P = (u64*)take((size_t)NWORDS * 8);
  u64* HS  = (u64*)take((size_t)NWORDS * 8);
  u64* T1H = (u64*)take((size_t)NWORDS * 8);
  u32* cntArr = (u32*)take(512 * 4);
  size_t zstart = off;
  u32* h1 = (u32*)take(2048 * 4);
  u32* h2 = (u32*)take(2048 * 4);
  u32* bars = (u32*)take(4 * 32 * 4);   // 4 barrier counters, one per 128-B line
  Ctrl* ctrl = (Ctrl*)take(sizeof(Ctrl));
  Acc* acc = (Acc*)take(sizeof(Acc));
  u32 zwords = (u32)((off - zstart) >> 2);

  // 3 dispatches: whole tail is one persistent kernel (relaxed-spin barriers).
  k_pre<<<512, 256, 0, stream>>>(tgt, P, cntArr, (u32*)(ws + zstart), zwords);
  k_ce_std<<<1088, 256, 0, stream>>>(feat, net, P, acc);
  k_simtail<<<512, 256, 0, stream>>>(feat, P, cntArr, acc, sim, h1, h2, T1P, HS, T1H, bars, ctrl, out);
}

// Round 5
// 525.452 us; speedup vs baseline: 1.6125x; 1.5666x over previous
//
#include <hip/hip_runtime.h>
#include <stdint.h>

typedef unsigned int u32;
typedef unsigned long long u64;
typedef float f4v __attribute__((ext_vector_type(4)));
typedef int i4v __attribute__((ext_vector_type(4)));

#define BB 2
#define CC 32
#define DD 64
#define HH 128
#define WW 128
#define SS (DD*HH*WW)        /* 1048576 */
#define NN (BB*SS)           /* 2097152 */
#define NQ (NN/4)            /* 524288 */
#define NWORDS (NN/64)       /* 32768 */
#define EPSF 1e-12f
#define TOPN 250u

struct Ctrl {
  u32 done4, tie, pad0, pad1;
};

struct Acc {
  double ce, tp, fp, fn;
  double stdsum[CC];
  double pos_num, mis_num, fin_num;
  u64 cnt, mcnt, fcnt;
};

// ---------- reduction helpers ----------
__device__ __forceinline__ float waveRedF(float v){
#pragma unroll
  for (int o = 32; o; o >>= 1) v += __shfl_xor(v, o);
  return v;
}
__device__ __forceinline__ u32 waveRedU(u32 v){
#pragma unroll
  for (int o = 32; o; o >>= 1) v += __shfl_xor(v, o);
  return v;
}
__device__ __forceinline__ void red_d(double* dst, float v, volatile float* sh){
  int lane = threadIdx.x & 63, wid = threadIdx.x >> 6;
  v = waveRedF(v);
  if (lane == 0) sh[wid] = v;
  __syncthreads();
  if (threadIdx.x == 0){
    float t = 0.f;
    for (int i = 0; i < (int)(blockDim.x >> 6); i++) t += sh[i];
    atomicAdd(dst, (double)t);
  }
  __syncthreads();
}
__device__ __forceinline__ void red_u(u64* dst, u32 v, volatile u32* sh){
  int lane = threadIdx.x & 63, wid = threadIdx.x >> 6;
  v = waveRedU(v);
  if (lane == 0) sh[wid] = v;
  __syncthreads();
  if (threadIdx.x == 0){
    u32 t = 0;
    for (int i = 0; i < (int)(blockDim.x >> 6); i++) t += sh[i];
    atomicAdd(dst, (u64)t);
  }
  __syncthreads();
}

__device__ __forceinline__ u32 sortkey(float f){
  u32 u = __float_as_uint(f);
  return (u & 0x80000000u) ? ~u : (u | 0x80000000u);
}

// Redundant per-block top-k bin selection from a finalized global histogram.
// (Histogram finalized by a PRIOR dispatch -> plain loads are coherent.)
__device__ __forceinline__ void select_top(const u32* __restrict__ hist, u32 nbins,
                                           u32 k, u32* shres, u32* binOut, u32* kremOut){
  __syncthreads();
  if (threadIdx.x < 64){
    int lane = threadIdx.x;
    u32 running = 0; bool found = false;
    for (u32 chunk = 0; chunk * 64 < nbins && !found; chunk++){
      int bin = (int)nbins - 1 - (int)(chunk * 64 + (u32)lane);
      u32 val = (bin >= 0) ? hist[bin] : 0u;
      u32 p = val;
#pragma unroll
      for (int o = 1; o < 64; o <<= 1){ u32 t = __shfl_up(p, o); if (lane >= o) p += t; }
      u32 tot = __shfl(p, 63);
      u32 incl = running + p, excl = incl - val;
      bool hit = (excl < k) && (incl >= k);
      u64 mb = __ballot(hit);
      if (mb){
        int hl = __ffsll((unsigned long long)mb) - 1;
        if (lane == hl){ shres[0] = (u32)bin; shres[1] = k - excl; }
        found = true;
      } else running += tot;
    }
    if (!found && lane == 0){ shres[0] = 0; shres[1] = k; }
  }
  __syncthreads();
  *binOut = shres[0]; *kremOut = shres[1];
}

// ---------- W+H slab dilation core (input already in LDS hsw[256]) ----------
__device__ __forceinline__ void dilwh_lds(const u64* hsw, u64* __restrict__ out,
                                          u32 slab, u64* arr){
  int t = threadIdx.x;
  if (t < 128){
    u64 lo = hsw[2 * t], hi = hsw[2 * t + 1];
    u64 al = lo, ah = hi;
#pragma unroll
    for (int i = 0; i < 10; i++){ u64 c = al >> 63; ah = ah | (ah << 1) | c; al = al | (al << 1); }
    u64 bl = lo, bh = hi;
#pragma unroll
    for (int i = 0; i < 10; i++){ u64 c = bh << 63; bl = bl | (bl >> 1) | c; bh = bh | (bh >> 1); }
    arr[2 * t] = al | bl;
    arr[2 * t + 1] = ah | bh;
  }
  __syncthreads();
  int h = t >> 1, wj = t & 1;
  int h0 = h - 10 > 0 ? h - 10 : 0;
  int h1 = h + 10 < 127 ? h + 10 : 127;
  u64 o = 0;
  for (int hh = h0; hh <= h1; hh++) o |= arr[2 * hh + wj];
  out[slab * 256u + (u32)t] = o;
  __syncthreads();
}

// ---------- W+H slab dilation from global input ----------
__device__ __forceinline__ void dilwh_slab(const u64* __restrict__ in, u64* __restrict__ out,
                                           u32 slab, u64* arr){
  u32 base = slab * 256u;
  int t = threadIdx.x;
  if (t < 128){
    u64 lo = in[base + 2 * t], hi = in[base + 2 * t + 1];
    u64 al = lo, ah = hi;
#pragma unroll
    for (int i = 0; i < 10; i++){ u64 c = al >> 63; ah = ah | (ah << 1) | c; al = al | (al << 1); }
    u64 bl = lo, bh = hi;
#pragma unroll
    for (int i = 0; i < 10; i++){ u64 c = bh << 63; bl = bl | (bl >> 1) | c; bh = bh | (bh >> 1); }
    arr[2 * t] = al | bl;
    arr[2 * t + 1] = ah | bh;
  }
  __syncthreads();
  int h = t >> 1, wj = t & 1;
  int h0 = h - 10 > 0 ? h - 10 : 0;
  int h1 = h + 10 < 127 ? h + 10 : 127;
  u64 o = 0;
  for (int hh = h0; hh <= h1; hh++) o |= arr[2 * hh + wj];
  out[base + (u32)t] = o;
  __syncthreads();
}

// ---------- K0: pbits from tgt + per-block pos counts + zero accumulators ----------
__global__ __launch_bounds__(256) void k_pre(const int* __restrict__ tgt,
                                             u64* __restrict__ pbits,
                                             u32* __restrict__ cntArr,
                                             u32* __restrict__ zptr, u32 zwords){
  __shared__ u32 nibsh[256];
  __shared__ u32 shu[4];
  if (blockIdx.x == 0){
    for (u32 i = threadIdx.x; i < zwords; i += 256u) zptr[i] = 0;
  }
  u32 cnt = 0;
#pragma unroll 1
  for (u32 it = 0; it < 4; it++){
    u32 q = blockIdx.x * 1024u + it * 256u + threadIdx.x;   // quad index
    i4v l4 = __builtin_nontemporal_load((const i4v*)(tgt + q * 4u));
    u32 nib = (l4.x ? 1u : 0u) | (l4.y ? 2u : 0u) | (l4.z ? 4u : 0u) | (l4.w ? 8u : 0u);
    cnt += __popc(nib);
    __syncthreads();             // protect nibsh reuse across iterations
    nibsh[threadIdx.x] = nib;
    __syncthreads();
    if (threadIdx.x < 16){
      u64 o = 0;
#pragma unroll
      for (int j = 0; j < 16; j++)
        o |= (u64)(nibsh[threadIdx.x * 16 + j] & 0xFu) << (4 * j);
      pbits[blockIdx.x * 64u + it * 16u + threadIdx.x] = o;
    }
  }
  int lane = threadIdx.x & 63, wid = threadIdx.x >> 6;
  cnt = waveRedU(cnt);
  if (lane == 0) shu[wid] = cnt;
  __syncthreads();
  if (threadIdx.x == 0) cntArr[blockIdx.x] = shu[0] + shu[1] + shu[2] + shu[3];
}

// ---------- K1: fused CE/dice + channel-major pos-sum of feature ----------
// Blocks 0..127: CE/dice over net (16 MB, NT loads). Blocks 128..2175: std
// pos-sums, each a SEQUENTIAL 128-KB run of one channel plane.
// 2176 blocks @ ~8/CU -> ~32 waves/CU for latency hiding (was 4/CU).
__global__ __launch_bounds__(256, 8) void k_ce_std(const float* __restrict__ feat,
                                                   const float* __restrict__ net,
                                                   const u64* __restrict__ pbits, Acc* acc){
  __shared__ float sh[16];
  if (blockIdx.x < 128u){
    u32 bid = blockIdx.x;
    float ce = 0.f, tp = 0.f, fp = 0.f, fnn = 0.f;
#pragma unroll 2
    for (u32 it = 0; it < 16; it++){
      u32 q = bid * 4096u + it * 256u + threadIdx.x;        // quad index
      u32 nib = (u32)(pbits[q >> 4] >> ((q & 15u) << 2)) & 0xFu;
      u32 v = q * 4u;
      u32 b = v >> 20, s = v & (SS - 1);
      const float* nb = net + (size_t)(b * 2) * SS + s;
      f4v x0 = __builtin_nontemporal_load((const f4v*)(nb));
      f4v x1 = __builtin_nontemporal_load((const f4v*)(nb + SS));
      float xs0[4] = {x0.x, x0.y, x0.z, x0.w};
      float xs1[4] = {x1.x, x1.y, x1.z, x1.w};
#pragma unroll
      for (int j = 0; j < 4; j++){
        int lab = (nib >> j) & 1;
        float m = fmaxf(xs0[j], xs1[j]);
        float lse = m + logf(expf(xs0[j] - m) + expf(xs1[j] - m));
        ce += lse - (lab ? xs1[j] : xs0[j]);
        float p1 = expf(xs1[j] - lse);
        if (lab){ tp += p1; fnn += 1.0f - p1; } else fp += p1;
      }
    }
    int lane = threadIdx.x & 63, wid = threadIdx.x >> 6;
    ce = waveRedF(ce); tp = waveRedF(tp); fp = waveRedF(fp); fnn = waveRedF(fnn);
    if (lane == 0){ sh[wid] = ce; sh[4 + wid] = tp; sh[8 + wid] = fp; sh[12 + wid] = fnn; }
    __syncthreads();
    if (threadIdx.x == 0){
      atomicAdd(&acc->ce, (double)(sh[0] + sh[1] + sh[2] + sh[3]));
      atomicAdd(&acc->tp, (double)(sh[4] + sh[5] + sh[6] + sh[7]));
      atomicAdd(&acc->fp, (double)(sh[8] + sh[9] + sh[10] + sh[11]));
      atomicAdd(&acc->fn, (double)(sh[12] + sh[13] + sh[14] + sh[15]));
    }
  } else {
    u32 bx = blockIdx.x - 128u;
    u32 c = bx & 31u;
    u32 chunk = bx >> 5;                // 0..63
    u32 vbase = chunk * 32768u;
    u32 b = vbase >> 20;
    u32 s0 = vbase & (SS - 1);
    const float* fp_ = feat + (size_t)b * CC * SS + (size_t)c * SS + s0;
    const u64* pb = pbits + (vbase >> 6);
    float a = 0.f;
#pragma unroll 4
    for (u32 i = 0; i < 32; i++){
      u32 off = i * 1024u + threadIdx.x * 4u;
      float4 f = *(const float4*)(fp_ + off);
      u32 bits = (u32)(pb[off >> 6] >> (off & 63u)) & 0xFu;
      if (bits & 1u) a += f.x;
      if (bits & 2u) a += f.y;
      if (bits & 4u) a += f.z;
      if (bits & 8u) a += f.w;
    }
    int lane = threadIdx.x & 63, wid = threadIdx.x >> 6;
    a = waveRedF(a);
    if (lane == 0) sh[wid] = a;
    __syncthreads();
    if (threadIdx.x == 0)
      atomicAdd(&acc->stdsum[c], (double)(sh[0] + sh[1] + sh[2] + sh[3]));
  }
}

// ---------- K2: sim via channel-outer loop, 2048 blocks x 1024 voxels ----------
// 8 blocks/CU (launch_bounds(256,8)) -> 32 waves/CU; unroll-4 c-loop keeps
// ~4 f4 loads in flight per thread. Fused: pos_num + level-1 hist.
__global__ __launch_bounds__(256, 8) void k_sim(const float* __restrict__ feat,
                                                const u64* __restrict__ pbits,
                                                const u32* __restrict__ cntArr,
                                                Acc* acc, float* __restrict__ sim,
                                                u32* __restrict__ h1){
  __shared__ float st[CC];
  __shared__ u32 lh[2048];
  __shared__ float shf[4];
  __shared__ u32 scnt;
  if (threadIdx.x < 64){
    u32 sc = 0;
#pragma unroll
    for (int i = 0; i < 8; i++) sc += cntArr[threadIdx.x * 8 + i];
    sc = waveRedU(sc);
    if (threadIdx.x == 0) scnt = sc;
  }
  __syncthreads();
  u32 cnt = scnt;
  if (blockIdx.x == 0 && threadIdx.x == 0) acc->cnt = (u64)cnt;
  {
    float sv = 0.f;
    if (threadIdx.x < CC && cnt) sv = (float)(acc->stdsum[threadIdx.x] / (double)cnt);
    if (threadIdx.x < 64){
      float t = waveRedF(sv * sv);
      float d = fmaxf(sqrtf(t), EPSF);
      if (threadIdx.x < CC) st[threadIdx.x] = sv / d;
    }
  }
  for (u32 i = threadIdx.x; i < 2048u; i += 256u) lh[i] = 0;
  __syncthreads();
  u32 vbase = blockIdx.x * 1024u;
  u32 b = vbase >> 20;
  u32 s0 = vbase & (SS - 1);
  const float* fp = feat + (size_t)b * CC * SS + s0 + threadIdx.x * 4u;
  float4 dt = {0.f, 0.f, 0.f, 0.f}, n2 = {0.f, 0.f, 0.f, 0.f};
#pragma unroll 4
  for (u32 c = 0; c < CC; c++){
    float w = st[c];
    float4 f = *(const float4*)(fp + (size_t)c * SS);
    dt.x += f.x * w; dt.y += f.y * w; dt.z += f.z * w; dt.w += f.w * w;
    n2.x += f.x * f.x; n2.y += f.y * f.y; n2.z += f.z * f.z; n2.w += f.w * f.w;
  }
  float pn = 0.f;
  {
    u32 v = vbase + threadIdx.x * 4u;
    float4 sm;
    sm.x = dt.x / fmaxf(sqrtf(n2.x), EPSF);
    sm.y = dt.y / fmaxf(sqrtf(n2.y), EPSF);
    sm.z = dt.z / fmaxf(sqrtf(n2.z), EPSF);
    sm.w = dt.w / fmaxf(sqrtf(n2.w), EPSF);
    *(float4*)(sim + v) = sm;
    u32 bits = (u32)(pbits[v >> 6] >> (v & 63u)) & 0xFu;
    float ss[4] = {sm.x, sm.y, sm.z, sm.w};
#pragma unroll
    for (int j = 0; j < 4; j++){
      if ((bits >> j) & 1u) pn += 1.f - ss[j];
      else atomicAdd(&lh[sortkey(ss[j]) >> 21], 1u);
    }
  }
  __syncthreads();
  for (u32 i = threadIdx.x; i < 2048u; i += 256u)
    if (lh[i]) atomicAdd(&h1[i], lh[i]);
  red_d(&acc->pos_num, pn, shf);
}

// ---------- K3: level-2 histogram + (blocks<128) W+H dilation of P ----------
__global__ __launch_bounds__(256) void k_histL2(const float* __restrict__ sim,
                                                const u64* __restrict__ pbits,
                                                const u32* __restrict__ h1,
                                                u32* __restrict__ h2,
                                                const u64* __restrict__ P,
                                                u64* __restrict__ T1P){
  __shared__ u64 arr[256];
  __shared__ u32 lh[2048];
  __shared__ u32 shres[2];
  if (blockIdx.x < 128u) dilwh_slab(P, T1P, blockIdx.x, arr);
  u32 p1, k1;
  select_top(h1, 2048, TOPN, shres, &p1, &k1);
  for (u32 i = threadIdx.x; i < 2048u; i += 256u) lh[i] = 0;
  __syncthreads();
  const u32 stride = 512u * 256u;
#pragma unroll 1
  for (u32 it = 0; it < 4; it++){
    u32 q = blockIdx.x * 256u + threadIdx.x + it * stride;
    u32 nib = (u32)(pbits[q >> 4] >> ((q & 15u) << 2)) & 0xFu;
    float4 s4 = *(const float4*)(sim + q * 4u);
    float ss[4] = {s4.x, s4.y, s4.z, s4.w};
#pragma unroll
    for (int j = 0; j < 4; j++){
      if (!((nib >> j) & 1u)){
        u32 key = sortkey(ss[j]);
        if ((key >> 21) == p1) atomicAdd(&lh[(key >> 10) & 2047u], 1u);
      }
    }
  }
  __syncthreads();
  for (u32 i = threadIdx.x; i < 2048u; i += 256u)
    if (lh[i]) atomicAdd(&h2[i], lh[i]);
}

// ---------- K4: fused mark + W+H dilation per slab ----------
// 128 blocks, one slab (b,d) each: mark 16384 voxels into LDS ballots, then
// dilate in LDS and write T1H directly. HS global buffer eliminated.
__global__ __launch_bounds__(256) void k_markdil(const float* __restrict__ sim,
                                                 const u64* __restrict__ pbits,
                                                 const u32* __restrict__ h1,
                                                 const u32* __restrict__ h2,
                                                 u64* __restrict__ T1H,
                                                 Ctrl* ctrl){
  __shared__ u32 shres[2];
  __shared__ u64 hsw[256];
  __shared__ u64 arr[256];
  u32 p1, k1, b2, k2;
  select_top(h1, 2048, TOPN, shres, &p1, &k1);
  select_top(h2, 2048, k1, shres, &b2, &k2);
  u32 p12 = (p1 << 11) | b2;
  int lane = threadIdx.x & 63, wid = threadIdx.x >> 6;
  u32 slab = blockIdx.x;
#pragma unroll 4
  for (u32 i = 0; i < 64; i++){
    u32 w = (u32)wid * 64u + i;                 // word index within slab
    u32 v = slab * 16384u + w * 64u + (u32)lane;
    u64 pw = pbits[v >> 6];
    bool neg = !((pw >> (v & 63u)) & 1ull);
    bool seed = false;
    if (neg){
      u32 pref = sortkey(sim[v]) >> 10;
      if (pref > p12) seed = true;
      else if (pref == p12){
        u32 old = atomicAdd(&ctrl->tie, 1u);
        if (old < k2) seed = true;
      }
    }
    u64 mb = __ballot(seed);
    if (lane == 0) hsw[w] = mb;
  }
  __syncthreads();
  dilwh_lds(hsw, T1H, slab, arr);
}

// ---------- K5: inline D-dilation of both masks + mis/fin sums + combine ----------
__global__ __launch_bounds__(256) void k_final(const float* __restrict__ sim,
                                               const u64* __restrict__ P,
                                               const u64* __restrict__ T1P,
                                               const u64* __restrict__ T1H,
                                               Acc* acc, Ctrl* ctrl, float* out){
  __shared__ float shf[4]; __shared__ u32 shu[4];
  __shared__ int amLast;
  u32 wi = blockIdx.x * 256u + threadIdx.x;   // one 64-voxel word per thread
  u32 wj = wi & 1u;
  u32 row = wi >> 1;                           // b*8192 + d*128 + h
  int h = (int)(row & 127u);
  int d = (int)((row >> 7) & 63u);
  u32 b = row >> 13;
  int d0 = d - 10 > 0 ? d - 10 : 0;
  int d1 = d + 10 < 63 ? d + 10 : 63;
  const u64* bp = T1P + ((size_t)(b << 13) + (u32)h) * 2 + wj;
  const u64* bh = T1H + ((size_t)(b << 13) + (u32)h) * 2 + wj;
  u64 dpw = 0, dhw = 0;
  for (int dd = d0; dd <= d1; dd++){
    dpw |= bp[(size_t)dd * 256];
    dhw |= bh[(size_t)dd * 256];
  }
  u64 pw = P[wi];
  u64 mis = dpw & ~pw;
  u64 fin = dhw & ~pw;
  float mn = 0.f, fnm = 0.f;
  u32 mc = (u32)__popcll(mis), fc = (u32)__popcll(fin);
  const float* sp = sim + (size_t)wi * 64u;
#pragma unroll 1
  for (int jj = 0; jj < 16; jj++){
    float4 s4 = *(const float4*)(sp + jj * 4);
    float ss[4] = {s4.x, s4.y, s4.z, s4.w};
#pragma unroll
    for (int j = 0; j < 4; j++){
      int bit = jj * 4 + j;
      float r = fmaxf(ss[j], 0.f);
      if ((mis >> bit) & 1ull) mn += r;
      if ((fin >> bit) & 1ull) fnm += r;
    }
  }
  red_d(&acc->mis_num, mn, shf);
  red_d(&acc->fin_num, fnm, shf);
  red_u(&acc->mcnt, mc, shu);
  red_u(&acc->fcnt, fc, shu);
  __threadfence();
  if (threadIdx.x == 0) amLast = (atomicAdd(&ctrl->done4, 1u) == gridDim.x - 1);
  __syncthreads();
  if (amLast && threadIdx.x == 0){
    double ce = acc->ce / (double)NN;
    double tp = acc->tp, fp = acc->fp, fn = acc->fn;
    double dc1 = (2.0 * tp + 1e-5) / (2.0 * tp + fp + fn + 1e-5 + 1e-8);
    u64 cnt = acc->cnt;
    double pos_loss = cnt ? (acc->pos_num / (double)cnt) : 0.0;
    u64 mcnt = atomicAdd(&acc->mcnt, 0ull);
    u64 fcnt = atomicAdd(&acc->fcnt, 0ull);
    double mis_loss = mcnt ? (atomicAdd(&acc->mis_num, 0.0) / (double)mcnt) : 0.0;
    double neg_loss = fcnt ? (atomicAdd(&acc->fin_num, 0.0) / (double)fcnt) : 0.0;
    out[0] = (float)(ce - dc1 + 5.0 * (pos_loss + mis_loss + neg_loss));
  }
}

extern "C" void kernel_launch(void* const* d_in, const int* in_sizes, int n_in,
                              void* d_out, int out_size, void* d_ws, size_t ws_size,
                              hipStream_t stream){
  (void)in_sizes; (void)n_in; (void)out_size; (void)ws_size;
  const float* feat = (const float*)d_in[0];
  const float* net  = (const float*)d_in[1];
  const int*   tgt  = (const int*)d_in[2];
  float* out = (float*)d_out;
  char* ws = (char*)d_ws;

  size_t off = 0;
  auto take = [&](size_t bytes) -> void* {
    void* p = (void*)(ws + off);
    off += (bytes + 255) & ~(size_t)255;
    return p;
  };
  float* sim = (float*)take((size_t)NN * 4);
  u64* P   = (u64*)take((size_t)NWORDS * 8);
  u64* T1P = (u64*)take((size_t)NWORDS * 8);
  u64* T1H = (u64*)take((size_t)NWORDS * 8);
  u32* cntArr = (u32*)take(512 * 4);
  size_t zstart = off;
  u32* h1 = (u32*)take(2048 * 4);
  u32* h2 = (u32*)take(2048 * 4);
  Ctrl* ctrl = (Ctrl*)take(sizeof(Ctrl));
  Acc* acc = (Acc*)take(sizeof(Acc));
  u32 zwords = (u32)((off - zstart) >> 2);

  // 6 dispatches. Back to multi-dispatch (persistent-kernel path abandoned:
  // device-scope fences cost >> dispatch gaps on gfx950). Big kernels now at
  // ~8 blocks/CU for read-latency hiding.
  k_pre<<<512, 256, 0, stream>>>(tgt, P, cntArr, (u32*)(ws + zstart), zwords);
  k_ce_std<<<2176, 256, 0, stream>>>(feat, net, P, acc);
  k_sim<<<2048, 256, 0, stream>>>(feat, P, cntArr, acc, sim, h1);
  k_histL2<<<512, 256, 0, stream>>>(sim, P, h1, h2, P, T1P);
  k_markdil<<<128, 256, 0, stream>>>(sim, P, h1, h2, T1H, ctrl);
  k_final<<<128, 256, 0, stream>>>(sim, P, T1P, T1H, acc, ctrl, out);
}

// Round 6
// 510.489 us; speedup vs baseline: 1.6597x; 1.0293x over previous
//
#include <hip/hip_runtime.h>
#include <stdint.h>

typedef unsigned int u32;
typedef unsigned long long u64;
typedef float f4v __attribute__((ext_vector_type(4)));
typedef int i4v __attribute__((ext_vector_type(4)));

#define BB 2
#define CC 32
#define DD 64
#define HH 128
#define WW 128
#define SS (DD*HH*WW)        /* 1048576 */
#define NN (BB*SS)           /* 2097152 */
#define NQ (NN/4)            /* 524288 */
#define NWORDS (NN/64)       /* 32768 */
#define EPSF 1e-12f
#define TOPN 250u

struct Ctrl {
  u32 done4, tie, pad0, pad1;
};

struct Acc {
  double ce, tp, fp, fn;
  double stdsum[CC];
  double pos_num, mis_num, fin_num;
  u64 cnt, mcnt, fcnt;
};

// ---------- reduction helpers ----------
__device__ __forceinline__ float waveRedF(float v){
#pragma unroll
  for (int o = 32; o; o >>= 1) v += __shfl_xor(v, o);
  return v;
}
__device__ __forceinline__ u32 waveRedU(u32 v){
#pragma unroll
  for (int o = 32; o; o >>= 1) v += __shfl_xor(v, o);
  return v;
}
__device__ __forceinline__ void red_d(double* dst, float v, volatile float* sh){
  int lane = threadIdx.x & 63, wid = threadIdx.x >> 6;
  v = waveRedF(v);
  if (lane == 0) sh[wid] = v;
  __syncthreads();
  if (threadIdx.x == 0){
    float t = 0.f;
    for (int i = 0; i < (int)(blockDim.x >> 6); i++) t += sh[i];
    atomicAdd(dst, (double)t);
  }
  __syncthreads();
}
__device__ __forceinline__ void red_u(u64* dst, u32 v, volatile u32* sh){
  int lane = threadIdx.x & 63, wid = threadIdx.x >> 6;
  v = waveRedU(v);
  if (lane == 0) sh[wid] = v;
  __syncthreads();
  if (threadIdx.x == 0){
    u32 t = 0;
    for (int i = 0; i < (int)(blockDim.x >> 6); i++) t += sh[i];
    atomicAdd(dst, (u64)t);
  }
  __syncthreads();
}

__device__ __forceinline__ u32 sortkey(float f){
  u32 u = __float_as_uint(f);
  return (u & 0x80000000u) ? ~u : (u | 0x80000000u);
}

// Redundant per-block top-k bin selection from a finalized global histogram.
// (Histogram finalized by a PRIOR dispatch -> plain loads are coherent.)
__device__ __forceinline__ void select_top(const u32* __restrict__ hist, u32 nbins,
                                           u32 k, u32* shres, u32* binOut, u32* kremOut){
  __syncthreads();
  if (threadIdx.x < 64){
    int lane = threadIdx.x;
    u32 running = 0; bool found = false;
    for (u32 chunk = 0; chunk * 64 < nbins && !found; chunk++){
      int bin = (int)nbins - 1 - (int)(chunk * 64 + (u32)lane);
      u32 val = (bin >= 0) ? hist[bin] : 0u;
      u32 p = val;
#pragma unroll
      for (int o = 1; o < 64; o <<= 1){ u32 t = __shfl_up(p, o); if (lane >= o) p += t; }
      u32 tot = __shfl(p, 63);
      u32 incl = running + p, excl = incl - val;
      bool hit = (excl < k) && (incl >= k);
      u64 mb = __ballot(hit);
      if (mb){
        int hl = __ffsll((unsigned long long)mb) - 1;
        if (lane == hl){ shres[0] = (u32)bin; shres[1] = k - excl; }
        found = true;
      } else running += tot;
    }
    if (!found && lane == 0){ shres[0] = 0; shres[1] = k; }
  }
  __syncthreads();
  *binOut = shres[0]; *kremOut = shres[1];
}

// ---------- W+H slab dilation core (input already in LDS hsw[256]) ----------
__device__ __forceinline__ void dilwh_lds(const u64* hsw, u64* __restrict__ out,
                                          u32 slab, u64* arr){
  int t = threadIdx.x;
  if (t < 128){
    u64 lo = hsw[2 * t], hi = hsw[2 * t + 1];
    u64 al = lo, ah = hi;
#pragma unroll
    for (int i = 0; i < 10; i++){ u64 c = al >> 63; ah = ah | (ah << 1) | c; al = al | (al << 1); }
    u64 bl = lo, bh = hi;
#pragma unroll
    for (int i = 0; i < 10; i++){ u64 c = bh << 63; bl = bl | (bl >> 1) | c; bh = bh | (bh >> 1); }
    arr[2 * t] = al | bl;
    arr[2 * t + 1] = ah | bh;
  }
  __syncthreads();
  int h = t >> 1, wj = t & 1;
  int h0 = h - 10 > 0 ? h - 10 : 0;
  int h1 = h + 10 < 127 ? h + 10 : 127;
  u64 o = 0;
  for (int hh = h0; hh <= h1; hh++) o |= arr[2 * hh + wj];
  out[slab * 256u + (u32)t] = o;
  __syncthreads();
}

// ---------- W+H slab dilation from global input ----------
__device__ __forceinline__ void dilwh_slab(const u64* __restrict__ in, u64* __restrict__ out,
                                           u32 slab, u64* arr){
  u32 base = slab * 256u;
  int t = threadIdx.x;
  if (t < 128){
    u64 lo = in[base + 2 * t], hi = in[base + 2 * t + 1];
    u64 al = lo, ah = hi;
#pragma unroll
    for (int i = 0; i < 10; i++){ u64 c = al >> 63; ah = ah | (ah << 1) | c; al = al | (al << 1); }
    u64 bl = lo, bh = hi;
#pragma unroll
    for (int i = 0; i < 10; i++){ u64 c = bh << 63; bl = bl | (bl >> 1) | c; bh = bh | (bh >> 1); }
    arr[2 * t] = al | bl;
    arr[2 * t + 1] = ah | bh;
  }
  __syncthreads();
  int h = t >> 1, wj = t & 1;
  int h0 = h - 10 > 0 ? h - 10 : 0;
  int h1 = h + 10 < 127 ? h + 10 : 127;
  u64 o = 0;
  for (int hh = h0; hh <= h1; hh++) o |= arr[2 * hh + wj];
  out[base + (u32)t] = o;
  __syncthreads();
}

// ---------- K0: pbits from tgt + per-block pos counts + zero accumulators ----------
__global__ __launch_bounds__(256) void k_pre(const int* __restrict__ tgt,
                                             u64* __restrict__ pbits,
                                             u32* __restrict__ cntArr,
                                             u32* __restrict__ zptr, u32 zwords){
  __shared__ u32 nibsh[256];
  __shared__ u32 shu[4];
  if (blockIdx.x == 0){
    for (u32 i = threadIdx.x; i < zwords; i += 256u) zptr[i] = 0;
  }
  u32 cnt = 0;
#pragma unroll 1
  for (u32 it = 0; it < 4; it++){
    u32 q = blockIdx.x * 1024u + it * 256u + threadIdx.x;   // quad index
    i4v l4 = __builtin_nontemporal_load((const i4v*)(tgt + q * 4u));
    u32 nib = (l4.x ? 1u : 0u) | (l4.y ? 2u : 0u) | (l4.z ? 4u : 0u) | (l4.w ? 8u : 0u);
    cnt += __popc(nib);
    __syncthreads();             // protect nibsh reuse across iterations
    nibsh[threadIdx.x] = nib;
    __syncthreads();
    if (threadIdx.x < 16){
      u64 o = 0;
#pragma unroll
      for (int j = 0; j < 16; j++)
        o |= (u64)(nibsh[threadIdx.x * 16 + j] & 0xFu) << (4 * j);
      pbits[blockIdx.x * 64u + it * 16u + threadIdx.x] = o;
    }
  }
  int lane = threadIdx.x & 63, wid = threadIdx.x >> 6;
  cnt = waveRedU(cnt);
  if (lane == 0) shu[wid] = cnt;
  __syncthreads();
  if (threadIdx.x == 0) cntArr[blockIdx.x] = shu[0] + shu[1] + shu[2] + shu[3];
}

// ---------- K1: fused CE/dice + channel-major pos-sum + P W+H dilation ----------
// Blocks 0..63: CE/dice over net (16 MB, NT loads), labels from pbits.
// Blocks 64..1087: std pos-sums, each a SEQUENTIAL 256-KB feature run.
// Blocks 1088..1215: W+H dilation of P -> T1P (depends only on pbits; rides
// free under the 256 MB feature stream, off histL2's critical path).
// R2-proven shapes; NO launch-bounds throttle (R5 lesson: (256,8) caps VGPRs
// at 64 and kills per-thread ILP -> +38 us regression).
__global__ __launch_bounds__(256) void k_ce_std(const float* __restrict__ feat,
                                                const float* __restrict__ net,
                                                const u64* __restrict__ pbits,
                                                u64* __restrict__ T1P, Acc* acc){
  __shared__ float sh[16];
  __shared__ u64 arr[256];
  if (blockIdx.x < 64u){
    u32 bid = blockIdx.x;
    float ce = 0.f, tp = 0.f, fp = 0.f, fnn = 0.f;
#pragma unroll 1
    for (u32 it = 0; it < 32; it++){
      u32 q = bid * 8192u + it * 256u + threadIdx.x;        // quad index
      u32 nib = (u32)(pbits[q >> 4] >> ((q & 15u) << 2)) & 0xFu;
      u32 v = q * 4u;
      u32 b = v >> 20, s = v & (SS - 1);
      const float* nb = net + (size_t)(b * 2) * SS + s;
      f4v x0 = __builtin_nontemporal_load((const f4v*)(nb));
      f4v x1 = __builtin_nontemporal_load((const f4v*)(nb + SS));
      float xs0[4] = {x0.x, x0.y, x0.z, x0.w};
      float xs1[4] = {x1.x, x1.y, x1.z, x1.w};
#pragma unroll
      for (int j = 0; j < 4; j++){
        int lab = (nib >> j) & 1;
        float m = fmaxf(xs0[j], xs1[j]);
        float lse = m + logf(expf(xs0[j] - m) + expf(xs1[j] - m));
        ce += lse - (lab ? xs1[j] : xs0[j]);
        float p1 = expf(xs1[j] - lse);
        if (lab){ tp += p1; fnn += 1.0f - p1; } else fp += p1;
      }
    }
    int lane = threadIdx.x & 63, wid = threadIdx.x >> 6;
    ce = waveRedF(ce); tp = waveRedF(tp); fp = waveRedF(fp); fnn = waveRedF(fnn);
    if (lane == 0){ sh[wid] = ce; sh[4 + wid] = tp; sh[8 + wid] = fp; sh[12 + wid] = fnn; }
    __syncthreads();
    if (threadIdx.x == 0){
      atomicAdd(&acc->ce, (double)(sh[0] + sh[1] + sh[2] + sh[3]));
      atomicAdd(&acc->tp, (double)(sh[4] + sh[5] + sh[6] + sh[7]));
      atomicAdd(&acc->fp, (double)(sh[8] + sh[9] + sh[10] + sh[11]));
      atomicAdd(&acc->fn, (double)(sh[12] + sh[13] + sh[14] + sh[15]));
    }
  } else if (blockIdx.x < 1088u){
    u32 bx = blockIdx.x - 64u;
    u32 c = bx & 31u;
    u32 chunk = bx >> 5;                // 0..31
    u32 vbase = chunk * 65536u;
    u32 b = vbase >> 20;
    u32 s0 = vbase & (SS - 1);
    const float* fp_ = feat + (size_t)b * CC * SS + (size_t)c * SS + s0;
    const u64* pb = pbits + (vbase >> 6);
    float a = 0.f;
#pragma unroll 8
    for (u32 i = 0; i < 64; i++){
      u32 off = i * 1024u + threadIdx.x * 4u;
      float4 f = *(const float4*)(fp_ + off);
      u32 bits = (u32)(pb[off >> 6] >> (off & 63u)) & 0xFu;
      if (bits & 1u) a += f.x;
      if (bits & 2u) a += f.y;
      if (bits & 4u) a += f.z;
      if (bits & 8u) a += f.w;
    }
    int lane = threadIdx.x & 63, wid = threadIdx.x >> 6;
    a = waveRedF(a);
    if (lane == 0) sh[wid] = a;
    __syncthreads();
    if (threadIdx.x == 0)
      atomicAdd(&acc->stdsum[c], (double)(sh[0] + sh[1] + sh[2] + sh[3]));
  } else {
    dilwh_slab(pbits, T1P, blockIdx.x - 1088u, arr);
  }
}

// ---------- K2: sim via register-blocked channel-outer loop (R2 shape) ----------
// 512 blocks x 4096 voxels; per channel a dense 16-KB window; dot/n2 in
// registers (4 float4 each). Fused: pos_num + level-1 hist.
__global__ __launch_bounds__(256) void k_sim(const float* __restrict__ feat,
                                             const u64* __restrict__ pbits,
                                             const u32* __restrict__ cntArr,
                                             Acc* acc, float* __restrict__ sim,
                                             u32* __restrict__ h1){
  __shared__ float st[CC];
  __shared__ u32 lh[2048];
  __shared__ float shf[4];
  __shared__ u32 scnt;
  if (threadIdx.x < 64){
    u32 sc = 0;
#pragma unroll
    for (int i = 0; i < 8; i++) sc += cntArr[threadIdx.x * 8 + i];
    sc = waveRedU(sc);
    if (threadIdx.x == 0) scnt = sc;
  }
  __syncthreads();
  u32 cnt = scnt;
  if (blockIdx.x == 0 && threadIdx.x == 0) acc->cnt = (u64)cnt;
  {
    float sv = 0.f;
    if (threadIdx.x < CC && cnt) sv = (float)(acc->stdsum[threadIdx.x] / (double)cnt);
    if (threadIdx.x < 64){
      float t = waveRedF(sv * sv);
      float d = fmaxf(sqrtf(t), EPSF);
      if (threadIdx.x < CC) st[threadIdx.x] = sv / d;
    }
  }
  for (u32 i = threadIdx.x; i < 2048u; i += 256u) lh[i] = 0;
  __syncthreads();
  u32 vbase = blockIdx.x * 4096u;
  u32 b = vbase >> 20;
  u32 s0 = vbase & (SS - 1);
  const float* fp = feat + (size_t)b * CC * SS + s0;
  float4 dt[4], n2[4];
#pragma unroll
  for (int g = 0; g < 4; g++){
    dt[g].x = dt[g].y = dt[g].z = dt[g].w = 0.f;
    n2[g].x = n2[g].y = n2[g].z = n2[g].w = 0.f;
  }
#pragma unroll 2
  for (u32 c = 0; c < CC; c++){
    float w = st[c];
    const float* fc = fp + (size_t)c * SS;
    float4 f[4];
#pragma unroll
    for (int g = 0; g < 4; g++)
      f[g] = *(const float4*)(fc + (u32)g * 1024u + threadIdx.x * 4u);
#pragma unroll
    for (int g = 0; g < 4; g++){
      dt[g].x += f[g].x * w; dt[g].y += f[g].y * w;
      dt[g].z += f[g].z * w; dt[g].w += f[g].w * w;
      n2[g].x += f[g].x * f[g].x; n2[g].y += f[g].y * f[g].y;
      n2[g].z += f[g].z * f[g].z; n2[g].w += f[g].w * f[g].w;
    }
  }
  float pn = 0.f;
#pragma unroll
  for (int g = 0; g < 4; g++){
    u32 off = (u32)g * 1024u + threadIdx.x * 4u;
    u32 v = vbase + off;
    float4 sm;
    sm.x = dt[g].x / fmaxf(sqrtf(n2[g].x), EPSF);
    sm.y = dt[g].y / fmaxf(sqrtf(n2[g].y), EPSF);
    sm.z = dt[g].z / fmaxf(sqrtf(n2[g].z), EPSF);
    sm.w = dt[g].w / fmaxf(sqrtf(n2[g].w), EPSF);
    *(float4*)(sim + v) = sm;
    u32 bits = (u32)(pbits[v >> 6] >> (v & 63u)) & 0xFu;
    float ss[4] = {sm.x, sm.y, sm.z, sm.w};
#pragma unroll
    for (int j = 0; j < 4; j++){
      if ((bits >> j) & 1u) pn += 1.f - ss[j];
      else atomicAdd(&lh[sortkey(ss[j]) >> 21], 1u);
    }
  }
  __syncthreads();
  for (u32 i = threadIdx.x; i < 2048u; i += 256u)
    if (lh[i]) atomicAdd(&h1[i], lh[i]);
  red_d(&acc->pos_num, pn, shf);
}

// ---------- K3: level-2 histogram (P-dilation moved to k_ce_std) ----------
__global__ __launch_bounds__(256) void k_hist2(const float* __restrict__ sim,
                                               const u64* __restrict__ pbits,
                                               const u32* __restrict__ h1,
                                               u32* __restrict__ h2){
  __shared__ u32 lh[2048];
  __shared__ u32 shres[2];
  u32 p1, k1;
  select_top(h1, 2048, TOPN, shres, &p1, &k1);
  for (u32 i = threadIdx.x; i < 2048u; i += 256u) lh[i] = 0;
  __syncthreads();
  const u32 stride = 512u * 256u;
#pragma unroll 1
  for (u32 it = 0; it < 4; it++){
    u32 q = blockIdx.x * 256u + threadIdx.x + it * stride;
    u32 nib = (u32)(pbits[q >> 4] >> ((q & 15u) << 2)) & 0xFu;
    float4 s4 = *(const float4*)(sim + q * 4u);
    float ss[4] = {s4.x, s4.y, s4.z, s4.w};
#pragma unroll
    for (int j = 0; j < 4; j++){
      if (!((nib >> j) & 1u)){
        u32 key = sortkey(ss[j]);
        if ((key >> 21) == p1) atomicAdd(&lh[(key >> 10) & 2047u], 1u);
      }
    }
  }
  __syncthreads();
  for (u32 i = threadIdx.x; i < 2048u; i += 256u)
    if (lh[i]) atomicAdd(&h2[i], lh[i]);
}

// ---------- K4: fused mark + W+H dilation per slab ----------
// 128 blocks, one slab (b,d) each: mark 16384 voxels into LDS ballots, then
// dilate in LDS and write T1H directly. HS global buffer eliminated.
__global__ __launch_bounds__(256) void k_markdil(const float* __restrict__ sim,
                                                 const u64* __restrict__ pbits,
                                                 const u32* __restrict__ h1,
                                                 const u32* __restrict__ h2,
                                                 u64* __restrict__ T1H,
                                                 Ctrl* ctrl){
  __shared__ u32 shres[2];
  __shared__ u64 hsw[256];
  __shared__ u64 arr[256];
  u32 p1, k1, b2, k2;
  select_top(h1, 2048, TOPN, shres, &p1, &k1);
  select_top(h2, 2048, k1, shres, &b2, &k2);
  u32 p12 = (p1 << 11) | b2;
  int lane = threadIdx.x & 63, wid = threadIdx.x >> 6;
  u32 slab = blockIdx.x;
#pragma unroll 4
  for (u32 i = 0; i < 64; i++){
    u32 w = (u32)wid * 64u + i;                 // word index within slab
    u32 v = slab * 16384u + w * 64u + (u32)lane;
    u64 pw = pbits[v >> 6];
    bool neg = !((pw >> (v & 63u)) & 1ull);
    bool seed = false;
    if (neg){
      u32 pref = sortkey(sim[v]) >> 10;
      if (pref > p12) seed = true;
      else if (pref == p12){
        u32 old = atomicAdd(&ctrl->tie, 1u);
        if (old < k2) seed = true;
      }
    }
    u64 mb = __ballot(seed);
    if (lane == 0) hsw[w] = mb;
  }
  __syncthreads();
  dilwh_lds(hsw, T1H, slab, arr);
}

// ---------- K5: inline D-dilation of both masks + mis/fin sums + combine ----------
__global__ __launch_bounds__(256) void k_final(const float* __restrict__ sim,
                                               const u64* __restrict__ P,
                                               const u64* __restrict__ T1P,
                                               const u64* __restrict__ T1H,
                                               Acc* acc, Ctrl* ctrl, float* out){
  __shared__ float shf[4]; __shared__ u32 shu[4];
  __shared__ int amLast;
  u32 wi = blockIdx.x * 256u + threadIdx.x;   // one 64-voxel word per thread
  u32 wj = wi & 1u;
  u32 row = wi >> 1;                           // b*8192 + d*128 + h
  int h = (int)(row & 127u);
  int d = (int)((row >> 7) & 63u);
  u32 b = row >> 13;
  int d0 = d - 10 > 0 ? d - 10 : 0;
  int d1 = d + 10 < 63 ? d + 10 : 63;
  const u64* bp = T1P + ((size_t)(b << 13) + (u32)h) * 2 + wj;
  const u64* bh = T1H + ((size_t)(b << 13) + (u32)h) * 2 + wj;
  u64 dpw = 0, dhw = 0;
  for (int dd = d0; dd <= d1; dd++){
    dpw |= bp[(size_t)dd * 256];
    dhw |= bh[(size_t)dd * 256];
  }
  u64 pw = P[wi];
  u64 mis = dpw & ~pw;
  u64 fin = dhw & ~pw;
  float mn = 0.f, fnm = 0.f;
  u32 mc = (u32)__popcll(mis), fc = (u32)__popcll(fin);
  const float* sp = sim + (size_t)wi * 64u;
#pragma unroll 1
  for (int jj = 0; jj < 16; jj++){
    float4 s4 = *(const float4*)(sp + jj * 4);
    float ss[4] = {s4.x, s4.y, s4.z, s4.w};
#pragma unroll
    for (int j = 0; j < 4; j++){
      int bit = jj * 4 + j;
      float r = fmaxf(ss[j], 0.f);
      if ((mis >> bit) & 1ull) mn += r;
      if ((fin >> bit) & 1ull) fnm += r;
    }
  }
  red_d(&acc->mis_num, mn, shf);
  red_d(&acc->fin_num, fnm, shf);
  red_u(&acc->mcnt, mc, shu);
  red_u(&acc->fcnt, fc, shu);
  __threadfence();
  if (threadIdx.x == 0) amLast = (atomicAdd(&ctrl->done4, 1u) == gridDim.x - 1);
  __syncthreads();
  if (amLast && threadIdx.x == 0){
    double ce = acc->ce / (double)NN;
    double tp = acc->tp, fp = acc->fp, fn = acc->fn;
    double dc1 = (2.0 * tp + 1e-5) / (2.0 * tp + fp + fn + 1e-5 + 1e-8);
    u64 cnt = acc->cnt;
    double pos_loss = cnt ? (acc->pos_num / (double)cnt) : 0.0;
    u64 mcnt = atomicAdd(&acc->mcnt, 0ull);
    u64 fcnt = atomicAdd(&acc->fcnt, 0ull);
    double mis_loss = mcnt ? (atomicAdd(&acc->mis_num, 0.0) / (double)mcnt) : 0.0;
    double neg_loss = fcnt ? (atomicAdd(&acc->fin_num, 0.0) / (double)fcnt) : 0.0;
    out[0] = (float)(ce - dc1 + 5.0 * (pos_loss + mis_loss + neg_loss));
  }
}

extern "C" void kernel_launch(void* const* d_in, const int* in_sizes, int n_in,
                              void* d_out, int out_size, void* d_ws, size_t ws_size,
                              hipStream_t stream){
  (void)in_sizes; (void)n_in; (void)out_size; (void)ws_size;
  const float* feat = (const float*)d_in[0];
  const float* net  = (const float*)d_in[1];
  const int*   tgt  = (const int*)d_in[2];
  float* out = (float*)d_out;
  char* ws = (char*)d_ws;

  size_t off = 0;
  auto take = [&](size_t bytes) -> void* {
    void* p = (void*)(ws + off);
    off += (bytes + 255) & ~(size_t)255;
    return p;
  };
  float* sim = (float*)take((size_t)NN * 4);
  u64* P   = (u64*)take((size_t)NWORDS * 8);
  u64* T1P = (u64*)take((size_t)NWORDS * 8);
  u64* T1H = (u64*)take((size_t)NWORDS * 8);
  u32* cntArr = (u32*)take(512 * 4);
  size_t zstart = off;
  u32* h1 = (u32*)take(2048 * 4);
  u32* h2 = (u32*)take(2048 * 4);
  Ctrl* ctrl = (Ctrl*)take(sizeof(Ctrl));
  Acc* acc = (Acc*)take(sizeof(Acc));
  u32 zwords = (u32)((off - zstart) >> 2);

  // 6 dispatches. R2-proven big-kernel shapes (no launch-bounds throttle);
  // markdil fusion kept; P-dilation rides inside k_ce_std.
  k_pre<<<512, 256, 0, stream>>>(tgt, P, cntArr, (u32*)(ws + zstart), zwords);
  k_ce_std<<<1216, 256, 0, stream>>>(feat, net, P, T1P, acc);
  k_sim<<<512, 256, 0, stream>>>(feat, P, cntArr, acc, sim, h1);
  k_hist2<<<512, 256, 0, stream>>>(sim, P, h1, h2);
  k_markdil<<<128, 256, 0, stream>>>(sim, P, h1, h2, T1H, ctrl);
  k_final<<<128, 256, 0, stream>>>(sim, P, T1P, T1H, acc, ctrl, out);
}